// Round 5
// baseline (243.791 us; speedup 1.0000x reference)
//
#include <hip/hip_runtime.h>
#include <math.h>

#define BB 4
#define NN 128
#define MM 16
#define KK 80
#define CF 256
#define CSL 2048
#define CT 2304      // CF + CSL
#define TFAST 32
#define TSLOW 8
#define HH 14
#define WW 14
#define HWQ 196      // 14*14
#define NQ4 49       // HWQ/4 float4 per (b,c)

// ---- workspace layout (float offsets) ----
#define G_OFF      0
#define G_SIZE     (BB*HWQ*KK)            // 62,720  G[b][cell][k]
#define FGF_OFF    (G_OFF + G_SIZE)       // 512 floats
#define ASSIGN_OFF (FGF_OFF + BB*NN)      // 512 ints (in float slots)
#define NUM_OFF    (ASSIGN_OFF + BB*NN)   // 4
#define CNT_OFF    (NUM_OFF + BB)         // 4
#define CTR_OFF    (CNT_OFF + BB)         // 4 ints (barrier/finalize counters)
#define P_OFF      (CTR_OFF + 8)          // padded

#define NSPLIT 64                          // chunks per b == partial count
#define MAXCH  43
#define P_SIZE (NSPLIT*G_SIZE)            // 4,014,080 floats = 16 MB
#define NBLK   (BB*NSPLIT)                // 256

__device__ __forceinline__ float logsig(float x) {
    return fminf(x, 0.f) - log1pf(expf(-fabsf(x)));
}

// device-scope grid barrier: all NBLK blocks co-resident (guaranteed: 256 blocks,
// 48KB LDS -> >=2 blocks/CU capacity on 256 CUs, all dispatched at t0)
__device__ __forceinline__ void gbarrier(int* ctr, int target) {
    __syncthreads();
    __threadfence();                       // release: each thread's stores -> device
    __syncthreads();
    if (threadIdx.x == 0) {
        atomicAdd(ctr, 1);
        while (__hip_atomic_load(ctr, __ATOMIC_RELAXED, __HIP_MEMORY_SCOPE_AGENT) < target)
            __builtin_amdgcn_s_sleep(1);
    }
    __syncthreads();
    __threadfence();                       // acquire
}

// ================= fused single kernel =================
__global__ __launch_bounds__(256) void k_all(const float* __restrict__ fastp,
                                             const float* __restrict__ slowp,
                                             const float* __restrict__ Wc,
                                             const float* __restrict__ props,
                                             const float* __restrict__ gtb,
                                             const float* __restrict__ gtc,
                                             const float* __restrict__ bcls,
                                             float* __restrict__ ws,
                                             float* __restrict__ out) {
    __shared__ float sfeat[MAXCH*HWQ + 64];   // +64 pad: j==6 overread guard
    __shared__ float sW[MAXCH*KK];
    __shared__ float sgt[BB*MM*4];
    __shared__ float sfgL[BB*NN];
    __shared__ int   sany;
    __shared__ int   cells[49];
    __shared__ float red[128];

    int blk = blockIdx.x;
    int tid = threadIdx.x;
    int b = blk >> 6;
    int r = blk & 63;
    int* ctr = (int*)ws + CTR_OFF;

    // ---------- phase 1: temporal mean -> LDS, GEMM, store partials ----------
    int gc0, nch, T, isfast;
    if (r < 16) { isfast = 1; gc0 = r * 16; nch = 16; T = TFAST; }
    else {
        int s = r - 16;
        int c0s = (s < 32) ? (43 * s) : (1376 + 42 * (s - 32));
        nch = (s < 32) ? 43 : 42;
        gc0 = CF + c0s; T = TSLOW; isfast = 0;
    }
    const float4* base = isfast
        ? ((const float4*)fastp + (size_t)(b * CF + gc0) * TFAST * NQ4)
        : ((const float4*)slowp + (size_t)(b * CSL + (gc0 - CF)) * TSLOW * NQ4);
    const float scale = 1.f / (float)T;
    int ntasks = nch * NQ4;
    for (int x = tid; x < ntasks; x += 256) {
        int cl = x / NQ4;
        int q  = x - cl * NQ4;
        const float4* p = base + (size_t)cl * T * NQ4 + q;
        float4 a = make_float4(0.f, 0.f, 0.f, 0.f);
        #pragma unroll 8
        for (int t = 0; t < T; ++t) {
            float4 v = p[t * NQ4];
            a.x += v.x; a.y += v.y; a.z += v.z; a.w += v.w;
        }
        a.x *= scale; a.y *= scale; a.z *= scale; a.w *= scale;
        ((float4*)sfeat)[cl * NQ4 + q] = a;
    }
    const float4* wsrc = (const float4*)Wc + (size_t)gc0 * (KK / 4);
    int wtasks = nch * (KK / 4);
    for (int x = tid; x < wtasks; x += 256) ((float4*)sW)[x] = wsrc[x];
    __syncthreads();

    int cg = tid & 31;
    int kq = tid >> 5;            // k0 = kq*10
    float acc[7][10];
    #pragma unroll
    for (int j = 0; j < 7; ++j)
        #pragma unroll
        for (int i = 0; i < 10; ++i) acc[j][i] = 0.f;
    const float* fr = sfeat + cg;
    const float* wr = sW + kq * 10;
    for (int c = 0; c < nch; ++c) {
        float w[10];
        #pragma unroll
        for (int i = 0; i < 10; ++i) w[i] = wr[c * KK + i];
        #pragma unroll
        for (int j = 0; j < 7; ++j) {
            float fv = fr[c * HWQ + 32 * j];   // j==6,cg>=4 hits pad: never stored
            #pragma unroll
            for (int i = 0; i < 10; ++i) acc[j][i] += fv * w[i];
        }
    }
    int k0 = kq * 10;
    {   // P[r][b][k][cell] — coalesced over cg
        float* P = ws + P_OFF + (size_t)r * G_SIZE + (size_t)b * (KK * HWQ);
        #pragma unroll
        for (int j = 0; j < 7; ++j) {
            int cell = cg + 32 * j;
            if (cell < HWQ) {
                #pragma unroll
                for (int i = 0; i < 10; ++i) P[(k0 + i) * HWQ + cell] = acc[j][i];
            }
        }
    }

    // ---------- phase 1b (block 0 only): IoU assignment ----------
    if (blk == 0) {
        if (tid < BB*MM*4) sgt[tid] = gtb[tid];
        if (tid == 0) sany = 0;
        __syncthreads();
        float best2[2]; int arg2[2];
        #pragma unroll
        for (int it = 0; it < 2; ++it) {
            int p = tid + 256 * it;
            int pb = p >> 7;
            float x1 = props[p*4+0], y1 = props[p*4+1], x2 = props[p*4+2], y2 = props[p*4+3];
            float aa = (x2 - x1) * (y2 - y1);
            float best = -1.f; int arg = 0;
            for (int m = 0; m < MM; ++m) {
                const float* g = &sgt[(pb*MM + m)*4];
                float tlx = fmaxf(x1, g[0]), tly = fmaxf(y1, g[1]);
                float brx = fminf(x2, g[2]), bry = fminf(y2, g[3]);
                float inter = fmaxf(brx - tlx, 0.f) * fmaxf(bry - tly, 0.f);
                float ab = (g[2] - g[0]) * (g[3] - g[1]);
                float iou = inter / (aa + ab - inter);
                if (iou > best) { best = iou; arg = m; }   // first-max = argmax
            }
            best2[it] = best; arg2[it] = arg;
            if (best >= 0.85f) atomicOr(&sany, 1);
        }
        __syncthreads();
        int any = sany;
        #pragma unroll
        for (int it = 0; it < 2; ++it) {
            int p = tid + 256 * it;
            float fg = any ? (best2[it] >= 0.85f ? 1.f : 0.f)
                           : (best2[it] >= 0.5f  ? 1.f : 0.f);
            sfgL[p] = fg;
            ws[FGF_OFF + p] = fg;
            ((int*)ws)[ASSIGN_OFF + p] = arg2[it];
        }
        __syncthreads();
        if (tid < BB) {
            float s = 0.f;
            for (int i = 0; i < NN; ++i) s += sfgL[tid*NN + i];
            ws[CNT_OFF + tid] = s;
            ws[NUM_OFF + tid] = 0.f;
        }
    }

    // ---------- barrier 1: all partials + assign visible ----------
    gbarrier(&ctr[0], NBLK);

    // ---------- phase 2: reduce partials into G[b][cell][k] ----------
    {
        int ridx = blk * 256 + tid;          // linear over [b][k][cell]
        if (ridx < G_SIZE) {
            const float* P = ws + P_OFF;
            float s = 0.f;
            #pragma unroll 16
            for (int cs = 0; cs < NSPLIT; ++cs) s += P[(size_t)cs * G_SIZE + ridx];
            int b2   = ridx / (KK * HWQ);
            int rem  = ridx - b2 * (KK * HWQ);
            int k    = rem / HWQ;
            int cell = rem - k * HWQ;
            ws[G_OFF + (size_t)b2 * HWQ * KK + cell * KK + k] = s;
        }
    }

    // ---------- barrier 2: G visible ----------
    gbarrier(&ctr[1], NBLK);

    // ---------- phase 3: per-proposal loss (2 proposals per block) ----------
    #pragma unroll
    for (int it = 0; it < 2; ++it) {
        int p = blk + 256 * it;
        int pb = p >> 7;
        float fgp = ws[FGF_OFF + p];         // uniform across block
        if (fgp != 0.f) {
            if (tid < 49) {
                int gy = tid / 7, gx = tid % 7;
                float x1 = props[p*4+0] * (1.f/16.f);
                float y1 = props[p*4+1] * (1.f/16.f);
                float x2 = props[p*4+2] * (1.f/16.f);
                float y2 = props[p*4+3] * (1.f/16.f);
                float gry = ((float)gy + 0.5f) / 7.f;
                float grx = ((float)gx + 0.5f) / 7.f;
                float cy = y1 + gry * (y2 - y1);
                float cx = x1 + grx * (x2 - x1);
                int iy = (int)floorf(cy); iy = min(max(iy, 0), HH-1);
                int ix = (int)floorf(cx); ix = min(max(ix, 0), WW-1);
                cells[tid] = iy * WW + ix;
            }
            __syncthreads();
            float lk = 0.f;
            if (tid < KK) {
                float a = 0.f;
                const float* Gb = ws + G_OFF + pb * HWQ * KK + tid;
                #pragma unroll 7
                for (int g = 0; g < 49; ++g) a += Gb[cells[g] * KK];
                float logit = a * (1.f/49.f) + bcls[tid];
                int asg = ((const int*)ws)[ASSIGN_OFF + p];
                float y = gtc[(pb*MM + asg)*KK + tid];
                lk = -(y * logsig(logit) + (1.f - y) * logsig(-logit));
            }
            if (tid < 128) red[tid] = (tid < KK) ? lk : 0.f;
            __syncthreads();
            for (int s = 64; s > 0; s >>= 1) {
                if (tid < s) red[tid] += red[tid + s];
                __syncthreads();
            }
            if (tid == 0) atomicAdd(&ws[NUM_OFF + pb], red[0] * (1.f/KK));
            __syncthreads();                 // cells/red reused next iteration
        }
    }

    // ---------- finalize: last block writes out[] ----------
    if (tid == 0) {
        __threadfence();
        int old = atomicAdd(&ctr[2], 1);
        if (old == NBLK - 1) {
            #pragma unroll
            for (int bb = 0; bb < BB; ++bb) {
                float num = atomicAdd(&ws[NUM_OFF + bb], 0.f);   // coherent read
                float c = ws[CNT_OFF + bb];
                out[bb] = (c > 0.f) ? num / c : 0.f;
            }
        }
    }
}

// ================= fallback path (ws too small for partials) =================
__global__ __launch_bounds__(256) void kz_zero(float* __restrict__ ws) {
    int idx = blockIdx.x * 256 + threadIdx.x;
    if (idx < G_SIZE) ws[G_OFF + idx] = 0.f;
}

__global__ __launch_bounds__(256) void k12_atomic(const float* __restrict__ fastp,
                                                  const float* __restrict__ slowp,
                                                  const float* __restrict__ Wc,
                                                  float* __restrict__ ws) {
    __shared__ float sfeat[MAXCH*HWQ + 64];
    __shared__ float sW[MAXCH*KK];
    int bid = blockIdx.x;
    int b = bid >> 6;
    int r = bid & 63;
    int gc0, nch, T, isfast;
    if (r < 16) { isfast = 1; gc0 = r * 16; nch = 16; T = TFAST; }
    else {
        int s = r - 16;
        int c0s = (s < 32) ? (43 * s) : (1376 + 42 * (s - 32));
        nch = (s < 32) ? 43 : 42;
        gc0 = CF + c0s; T = TSLOW; isfast = 0;
    }
    int tid = threadIdx.x;
    const float4* base = isfast
        ? ((const float4*)fastp + (size_t)(b * CF + gc0) * TFAST * NQ4)
        : ((const float4*)slowp + (size_t)(b * CSL + (gc0 - CF)) * TSLOW * NQ4);
    const float scale = 1.f / (float)T;
    int ntasks = nch * NQ4;
    for (int x = tid; x < ntasks; x += 256) {
        int cl = x / NQ4;
        int q  = x - cl * NQ4;
        const float4* p = base + (size_t)cl * T * NQ4 + q;
        float4 a = make_float4(0.f, 0.f, 0.f, 0.f);
        #pragma unroll 8
        for (int t = 0; t < T; ++t) {
            float4 v = p[t * NQ4];
            a.x += v.x; a.y += v.y; a.z += v.z; a.w += v.w;
        }
        a.x *= scale; a.y *= scale; a.z *= scale; a.w *= scale;
        ((float4*)sfeat)[cl * NQ4 + q] = a;
    }
    const float4* wsrc = (const float4*)Wc + (size_t)gc0 * (KK / 4);
    int wtasks = nch * (KK / 4);
    for (int x = tid; x < wtasks; x += 256) ((float4*)sW)[x] = wsrc[x];
    __syncthreads();
    int cg = tid & 31;
    int kq = tid >> 5;
    float acc[7][10];
    #pragma unroll
    for (int j = 0; j < 7; ++j)
        #pragma unroll
        for (int i = 0; i < 10; ++i) acc[j][i] = 0.f;
    const float* fr = sfeat + cg;
    const float* wr = sW + kq * 10;
    for (int c = 0; c < nch; ++c) {
        float w[10];
        #pragma unroll
        for (int i = 0; i < 10; ++i) w[i] = wr[c * KK + i];
        #pragma unroll
        for (int j = 0; j < 7; ++j) {
            float fv = fr[c * HWQ + 32 * j];
            #pragma unroll
            for (int i = 0; i < 10; ++i) acc[j][i] += fv * w[i];
        }
    }
    int k0 = kq * 10;
    float* g = ws + G_OFF + (size_t)b * HWQ * KK;
    #pragma unroll
    for (int j = 0; j < 7; ++j) {
        int cell = cg + 32 * j;
        if (cell < HWQ) {
            #pragma unroll
            for (int i = 0; i < 10; ++i) atomicAdd(&g[cell * KK + k0 + i], acc[j][i]);
        }
    }
}

__global__ __launch_bounds__(512) void kb_assign(const float* __restrict__ props,
                                                 const float* __restrict__ gtb,
                                                 float* __restrict__ ws) {
    __shared__ float sgt[BB*MM*4];
    __shared__ float sfg[BB*NN];
    __shared__ int sany;
    int t = threadIdx.x;
    if (t < BB*MM*4) sgt[t] = gtb[t];
    if (t == 0) sany = 0;
    __syncthreads();
    int b = t >> 7;
    float x1 = props[t*4+0], y1 = props[t*4+1], x2 = props[t*4+2], y2 = props[t*4+3];
    float aa = (x2 - x1) * (y2 - y1);
    float best = -1.f; int arg = 0;
    for (int m = 0; m < MM; ++m) {
        const float* g = &sgt[(b*MM + m)*4];
        float tlx = fmaxf(x1, g[0]), tly = fmaxf(y1, g[1]);
        float brx = fminf(x2, g[2]), bry = fminf(y2, g[3]);
        float inter = fmaxf(brx - tlx, 0.f) * fmaxf(bry - tly, 0.f);
        float ab = (g[2] - g[0]) * (g[3] - g[1]);
        float iou = inter / (aa + ab - inter);
        if (iou > best) { best = iou; arg = m; }
    }
    if (best >= 0.85f) atomicOr(&sany, 1);
    __syncthreads();
    float fg = sany ? (best >= 0.85f ? 1.f : 0.f) : (best >= 0.5f ? 1.f : 0.f);
    sfg[t] = fg;
    ws[FGF_OFF + t] = fg;
    ((int*)ws)[ASSIGN_OFF + t] = arg;
    __syncthreads();
    if (t < BB) {
        float s = 0.f;
        for (int i = 0; i < NN; ++i) s += sfg[t*NN + i];
        ws[CNT_OFF + t] = s;
        ws[NUM_OFF + t] = 0.f;
    }
    if (t == 0) ((int*)ws)[CTR_OFF + 2] = 0;
}

__global__ __launch_bounds__(128) void k3b_loss(const float* __restrict__ props,
                                                const float* __restrict__ gtc,
                                                const float* __restrict__ bcls,
                                                float* __restrict__ ws,
                                                float* __restrict__ out) {
    int p = blockIdx.x;
    int b = p >> 7;
    int t = threadIdx.x;
    __shared__ int cells[49];
    __shared__ float red[128];
    if (ws[FGF_OFF + p] != 0.f) {
        if (t < 49) {
            int gy = t / 7, gx = t % 7;
            float x1 = props[p*4+0] * (1.f/16.f);
            float y1 = props[p*4+1] * (1.f/16.f);
            float x2 = props[p*4+2] * (1.f/16.f);
            float y2 = props[p*4+3] * (1.f/16.f);
            float gry = ((float)gy + 0.5f) / 7.f;
            float grx = ((float)gx + 0.5f) / 7.f;
            float cy = y1 + gry * (y2 - y1);
            float cx = x1 + grx * (x2 - x1);
            int iy = (int)floorf(cy); iy = min(max(iy, 0), HH-1);
            int ix = (int)floorf(cx); ix = min(max(ix, 0), WW-1);
            cells[t] = iy * WW + ix;
        }
        __syncthreads();
        float lk = 0.f;
        if (t < KK) {
            float a = 0.f;
            const float* Gb = ws + G_OFF + b * HWQ * KK + t;
            #pragma unroll 7
            for (int g = 0; g < 49; ++g) a += Gb[cells[g] * KK];
            float logit = a * (1.f/49.f) + bcls[t];
            int asg = ((const int*)ws)[ASSIGN_OFF + p];
            float y = gtc[(b*MM + asg)*KK + t];
            lk = -(y * logsig(logit) + (1.f - y) * logsig(-logit));
        }
        red[t] = lk;
        __syncthreads();
        for (int s = 64; s > 0; s >>= 1) {
            if (t < s) red[t] += red[t + s];
            __syncthreads();
        }
        if (t == 0) atomicAdd(&ws[NUM_OFF + b], red[0] * (1.f/KK));
    }
    if (t == 0) {
        __threadfence();
        int old = atomicAdd(&((int*)ws)[CTR_OFF + 2], 1);
        if (old == BB*NN - 1) {
            __threadfence();
            #pragma unroll
            for (int bb = 0; bb < BB; ++bb) {
                float num = atomicAdd(&ws[NUM_OFF + bb], 0.f);
                float c = ws[CNT_OFF + bb];
                out[bb] = (c > 0.f) ? num / c : 0.f;
            }
        }
    }
}

extern "C" void kernel_launch(void* const* d_in, const int* in_sizes, int n_in,
                              void* d_out, int out_size, void* d_ws, size_t ws_size,
                              hipStream_t stream) {
    const float* fastp = (const float*)d_in[0];
    const float* slowp = (const float*)d_in[1];
    const float* props = (const float*)d_in[2];
    const float* gtb   = (const float*)d_in[3];
    const float* gtc   = (const float*)d_in[4];
    const float* Wc    = (const float*)d_in[5];
    const float* bcls  = (const float*)d_in[6];
    float* ws  = (float*)d_ws;
    float* out = (float*)d_out;

    const size_t need = (size_t)(P_OFF + P_SIZE) * sizeof(float);
    const int use_partials = (ws_size >= need) ? 1 : 0;   // deterministic -> graph-safe

    if (use_partials) {
        // zero the 4 barrier/finalize counters (graph-legal async memset)
        hipMemsetAsync((char*)d_ws + (size_t)CTR_OFF * sizeof(float), 0,
                       4 * sizeof(int), stream);
        k_all<<<NBLK, 256, 0, stream>>>(fastp, slowp, Wc, props, gtb, gtc, bcls, ws, out);
    } else {
        kz_zero<<<(G_SIZE + 255)/256, 256, 0, stream>>>(ws);
        k12_atomic<<<BB * NSPLIT, 256, 0, stream>>>(fastp, slowp, Wc, ws);
        kb_assign<<<1, 512, 0, stream>>>(props, gtb, ws);
        k3b_loss<<<BB*NN, 128, 0, stream>>>(props, gtc, bcls, ws, out);
    }
}

// Round 6
// 139.076 us; speedup vs baseline: 1.7529x; 1.7529x over previous
//
#include <hip/hip_runtime.h>
#include <math.h>

#define BB 4
#define NN 128
#define MM 16
#define KK 80
#define CF 256
#define CSL 2048
#define CT 2304      // CF + CSL
#define TFAST 32
#define TSLOW 8
#define HH 14
#define WW 14
#define HWQ 196      // 14*14
#define NQ4 49       // HWQ/4 float4 per (b,c)

// ---- workspace layout (float offsets) ----
#define G_OFF      0
#define G_SIZE     (BB*HWQ*KK)            // 62,720  G[b][cell][k]
#define FGF_OFF    (G_OFF + G_SIZE)       // 512 floats
#define ASSIGN_OFF (FGF_OFF + BB*NN)      // 512 ints (in float slots)
#define NUM_OFF    (ASSIGN_OFF + BB*NN)   // 4
#define CNT_OFF    (NUM_OFF + BB)         // 4
#define CTR_OFF    (CNT_OFF + BB)         // 1 int (k3b finalize counter)
#define P_OFF      (CTR_OFF + 8)          // padded

#define NSPLIT 64                          // chunks per b == partial count
#define MAXCH  43
#define P_SIZE (NSPLIT*G_SIZE)            // 4,014,080 floats = 16 MB

// ---------------- K12: fused temporal-mean + split-C GEMM ----------------
// grid 256 = b(4) x chunk(64). Chunk table (per b): r<16 -> fast, 16 ch;
// r>=16 -> slow, 43 ch (32 chunks) then 42 ch (16 chunks).
// NOTE (R5 lesson): do NOT fuse across the P->G dependency with in-kernel
// device barriers — agent-scope fences invalidate per-XCD L2 and cost ~130us.
__global__ __launch_bounds__(256) void k12_fused(const float* __restrict__ fastp,
                                                 const float* __restrict__ slowp,
                                                 const float* __restrict__ Wc,
                                                 float* __restrict__ ws,
                                                 int use_partials) {
    __shared__ float sfeat[MAXCH*HWQ + 64];   // +64 pad: j==6 overread guard
    __shared__ float sW[MAXCH*KK];
    int bid = blockIdx.x;
    int b = bid >> 6;
    int r = bid & 63;
    int gc0, nch, T, isfast;
    if (r < 16) { isfast = 1; gc0 = r * 16; nch = 16; T = TFAST; }
    else {
        int s = r - 16;
        int c0s = (s < 32) ? (43 * s) : (1376 + 42 * (s - 32));
        nch = (s < 32) ? 43 : 42;
        gc0 = CF + c0s; T = TSLOW; isfast = 0;
    }
    int tid = threadIdx.x;

    const float4* base = isfast
        ? ((const float4*)fastp + (size_t)(b * CF + gc0) * TFAST * NQ4)
        : ((const float4*)slowp + (size_t)(b * CSL + (gc0 - CF)) * TSLOW * NQ4);
    const float scale = 1.f / (float)T;
    int ntasks = nch * NQ4;
    for (int x = tid; x < ntasks; x += 256) {
        int cl = x / NQ4;
        int q  = x - cl * NQ4;
        const float4* p = base + (size_t)cl * T * NQ4 + q;
        float4 a = make_float4(0.f, 0.f, 0.f, 0.f);
        #pragma unroll 8
        for (int t = 0; t < T; ++t) {
            float4 v = p[t * NQ4];
            a.x += v.x; a.y += v.y; a.z += v.z; a.w += v.w;
        }
        a.x *= scale; a.y *= scale; a.z *= scale; a.w *= scale;
        ((float4*)sfeat)[cl * NQ4 + q] = a;
    }
    const float4* wsrc = (const float4*)Wc + (size_t)gc0 * (KK / 4);
    int wtasks = nch * (KK / 4);
    for (int x = tid; x < wtasks; x += 256) ((float4*)sW)[x] = wsrc[x];
    __syncthreads();

    int cg = tid & 31;
    int kq = tid >> 5;            // k0 = kq*10
    float acc[7][10];
    #pragma unroll
    for (int j = 0; j < 7; ++j)
        #pragma unroll
        for (int i = 0; i < 10; ++i) acc[j][i] = 0.f;

    const float* fr = sfeat + cg;
    const float* wr = sW + kq * 10;
    for (int c = 0; c < nch; ++c) {
        float w[10];
        #pragma unroll
        for (int i = 0; i < 10; ++i) w[i] = wr[c * KK + i];
        #pragma unroll
        for (int j = 0; j < 7; ++j) {
            float fv = fr[c * HWQ + 32 * j];   // j==6,cg>=4 hits pad: never stored
            #pragma unroll
            for (int i = 0; i < 10; ++i) acc[j][i] += fv * w[i];
        }
    }

    int k0 = kq * 10;
    if (use_partials) {
        // P[r][b][k][cell] — coalesced over cg
        float* P = ws + P_OFF + (size_t)r * G_SIZE + (size_t)b * (KK * HWQ);
        #pragma unroll
        for (int j = 0; j < 7; ++j) {
            int cell = cg + 32 * j;
            if (cell < HWQ) {
                #pragma unroll
                for (int i = 0; i < 10; ++i) P[(k0 + i) * HWQ + cell] = acc[j][i];
            }
        }
    } else {
        float* g = ws + G_OFF + (size_t)b * HWQ * KK;
        #pragma unroll
        for (int j = 0; j < 7; ++j) {
            int cell = cg + 32 * j;
            if (cell < HWQ) {
                #pragma unroll
                for (int i = 0; i < 10; ++i) atomicAdd(&g[cell * KK + k0 + i], acc[j][i]);
            }
        }
    }
}

// ---------------- fallback: zero G (only when ws too small for P) ----------------
__global__ __launch_bounds__(256) void kz_zero(float* __restrict__ ws) {
    int idx = blockIdx.x * 256 + threadIdx.x;
    if (idx < G_SIZE) ws[G_OFF + idx] = 0.f;
}

// ---------------- K2b: reduce partials (256-thr blocks) + IoU assign (last block) ----
#define RED_BLOCKS ((G_SIZE + 255) / 256)   // 245
__global__ __launch_bounds__(256) void k2b_assign(const float* __restrict__ props,
                                                  const float* __restrict__ gtb,
                                                  float* __restrict__ ws,
                                                  int use_partials) {
    int blk = blockIdx.x;
    int t = threadIdx.x;
    if (blk < RED_BLOCKS) {
        if (!use_partials) return;
        int ridx = blk * 256 + t;            // linear over [b][k][cell]
        if (ridx < G_SIZE) {
            const float* P = ws + P_OFF;
            float s = 0.f;
            #pragma unroll 16
            for (int cs = 0; cs < NSPLIT; ++cs) s += P[(size_t)cs * G_SIZE + ridx];
            int b    = ridx / (KK * HWQ);
            int rem  = ridx - b * (KK * HWQ);
            int k    = rem / HWQ;
            int cell = rem - k * HWQ;
            ws[G_OFF + (size_t)b * HWQ * KK + cell * KK + k] = s;  // G[b][cell][k]
        }
        return;
    }
    // ---- assignment block (256 threads, 2 proposals each; validated in R5) ----
    __shared__ float sgt[BB*MM*4];
    __shared__ float sfg[BB*NN];
    __shared__ int sany;
    if (t < BB*MM*4) sgt[t] = gtb[t];
    if (t == 0) sany = 0;
    __syncthreads();
    float best2[2]; int arg2[2];
    #pragma unroll
    for (int it = 0; it < 2; ++it) {
        int p = t + 256 * it;
        int pb = p >> 7;
        float x1 = props[p*4+0], y1 = props[p*4+1], x2 = props[p*4+2], y2 = props[p*4+3];
        float aa = (x2 - x1) * (y2 - y1);
        float best = -1.f; int arg = 0;
        for (int m = 0; m < MM; ++m) {
            const float* g = &sgt[(pb*MM + m)*4];
            float tlx = fmaxf(x1, g[0]), tly = fmaxf(y1, g[1]);
            float brx = fminf(x2, g[2]), bry = fminf(y2, g[3]);
            float inter = fmaxf(brx - tlx, 0.f) * fmaxf(bry - tly, 0.f);
            float ab = (g[2] - g[0]) * (g[3] - g[1]);
            float iou = inter / (aa + ab - inter);
            if (iou > best) { best = iou; arg = m; }   // first-max = argmax
        }
        best2[it] = best; arg2[it] = arg;
        if (best >= 0.85f) atomicOr(&sany, 1);
    }
    __syncthreads();
    int any = sany;
    #pragma unroll
    for (int it = 0; it < 2; ++it) {
        int p = t + 256 * it;
        float fg = any ? (best2[it] >= 0.85f ? 1.f : 0.f)
                       : (best2[it] >= 0.5f  ? 1.f : 0.f);
        sfg[p] = fg;
        ws[FGF_OFF + p] = fg;
        ((int*)ws)[ASSIGN_OFF + p] = arg2[it];
    }
    __syncthreads();
    if (t < BB) {
        float s = 0.f;
        for (int i = 0; i < NN; ++i) s += sfg[t*NN + i];
        ws[CNT_OFF + t] = s;
        ws[NUM_OFF + t] = 0.f;
    }
    if (t == 0) ((int*)ws)[CTR_OFF] = 0;
}

// ---------------- K3b: per-proposal loss + last-block finalize ----------------
__device__ __forceinline__ float logsig(float x) {
    return fminf(x, 0.f) - log1pf(expf(-fabsf(x)));
}

__global__ __launch_bounds__(128) void k3b_loss(const float* __restrict__ props,
                                                const float* __restrict__ gtc,
                                                const float* __restrict__ bcls,
                                                float* __restrict__ ws,
                                                float* __restrict__ out) {
    int p = blockIdx.x;
    int b = p >> 7;
    int t = threadIdx.x;
    __shared__ int cells[49];
    __shared__ float red[128];
    if (ws[FGF_OFF + p] != 0.f) {
        if (t < 49) {
            int gy = t / 7, gx = t % 7;
            float x1 = props[p*4+0] * (1.f/16.f);
            float y1 = props[p*4+1] * (1.f/16.f);
            float x2 = props[p*4+2] * (1.f/16.f);
            float y2 = props[p*4+3] * (1.f/16.f);
            float gry = ((float)gy + 0.5f) / 7.f;
            float grx = ((float)gx + 0.5f) / 7.f;
            float cy = y1 + gry * (y2 - y1);
            float cx = x1 + grx * (x2 - x1);
            int iy = (int)floorf(cy); iy = min(max(iy, 0), HH-1);
            int ix = (int)floorf(cx); ix = min(max(ix, 0), WW-1);
            cells[t] = iy * WW + ix;
        }
        __syncthreads();
        float lk = 0.f;
        if (t < KK) {
            float a = 0.f;
            const float* Gb = ws + G_OFF + b * HWQ * KK + t;
            #pragma unroll 7
            for (int g = 0; g < 49; ++g) a += Gb[cells[g] * KK];
            float logit = a * (1.f/49.f) + bcls[t];
            int asg = ((const int*)ws)[ASSIGN_OFF + p];
            float y = gtc[(b*MM + asg)*KK + t];
            lk = -(y * logsig(logit) + (1.f - y) * logsig(-logit));
        }
        red[t] = lk;
        __syncthreads();
        for (int s = 64; s > 0; s >>= 1) {
            if (t < s) red[t] += red[t + s];
            __syncthreads();
        }
        if (t == 0) atomicAdd(&ws[NUM_OFF + b], red[0] * (1.f/KK));
    }
    if (t == 0) {
        __threadfence();
        int old = atomicAdd(&((int*)ws)[CTR_OFF], 1);
        if (old == BB*NN - 1) {
            __threadfence();
            #pragma unroll
            for (int bb = 0; bb < BB; ++bb) {
                float num = atomicAdd(&ws[NUM_OFF + bb], 0.f);
                float c = ws[CNT_OFF + bb];
                out[bb] = (c > 0.f) ? num / c : 0.f;
            }
        }
    }
}

extern "C" void kernel_launch(void* const* d_in, const int* in_sizes, int n_in,
                              void* d_out, int out_size, void* d_ws, size_t ws_size,
                              hipStream_t stream) {
    const float* fastp = (const float*)d_in[0];
    const float* slowp = (const float*)d_in[1];
    const float* props = (const float*)d_in[2];
    const float* gtb   = (const float*)d_in[3];
    const float* gtc   = (const float*)d_in[4];
    const float* Wc    = (const float*)d_in[5];
    const float* bcls  = (const float*)d_in[6];
    float* ws  = (float*)d_ws;
    float* out = (float*)d_out;

    const size_t need = (size_t)(P_OFF + P_SIZE) * sizeof(float);
    const int use_partials = (ws_size >= need) ? 1 : 0;   // deterministic -> graph-safe

    if (!use_partials)
        kz_zero<<<(G_SIZE + 255)/256, 256, 0, stream>>>(ws);
    k12_fused<<<BB * NSPLIT, 256, 0, stream>>>(fastp, slowp, Wc, ws, use_partials);
    k2b_assign<<<RED_BLOCKS + 1, 256, 0, stream>>>(props, gtb, ws, use_partials);
    k3b_loss<<<BB*NN, 128, 0, stream>>>(props, gtc, bcls, ws, out);
}

// Round 7
// 134.929 us; speedup vs baseline: 1.8068x; 1.0307x over previous
//
#include <hip/hip_runtime.h>
#include <math.h>

#define BB 4
#define NN 128
#define MM 16
#define KK 80
#define CF 256
#define CSL 2048
#define CT 2304      // CF + CSL
#define TFAST 32
#define TSLOW 8
#define HH 14
#define WW 14
#define HWQ 196      // 14*14
#define NQ4 49       // HWQ/4 float4 per (b,c)

// ---- workspace layout (float offsets) ----
#define G_OFF      0
#define G_SIZE     (BB*HWQ*KK)            // 62,720  G[b][cell][k]
#define FGF_OFF    (G_OFF + G_SIZE)       // 512 floats
#define ASSIGN_OFF (FGF_OFF + BB*NN)      // 512 ints (in float slots)
#define NUM_OFF    (ASSIGN_OFF + BB*NN)   // 4
#define CNT_OFF    (NUM_OFF + BB)         // 4
#define CTR_OFF    (CNT_OFF + BB)         // 1 int (k3b finalize counter)
#define P_OFF      (CTR_OFF + 8)          // padded

#define NSPLIT 64                          // chunks per b == partial count
#define MAXCH  43
#define P_SIZE (NSPLIT*G_SIZE)            // 4,014,080 floats = 16 MB

// ---------------- K12: fused temporal-mean + split-C GEMM ----------------
// grid 256 = b(4) x chunk(64). Chunk table (per b): r<16 -> fast, 16 ch;
// r>=16 -> slow, 43 ch (32 chunks) then 42 ch (16 chunks).
// NOTE (R5 lesson): do NOT fuse across the P->G dependency with in-kernel
// device barriers — agent-scope fences invalidate per-XCD L2 and cost ~130us.
__global__ __launch_bounds__(256) void k12_fused(const float* __restrict__ fastp,
                                                 const float* __restrict__ slowp,
                                                 const float* __restrict__ Wc,
                                                 float* __restrict__ ws,
                                                 int use_partials) {
    __shared__ float sfeat[MAXCH*HWQ + 64];   // +64 pad: j==6 overread guard
    __shared__ float sW[MAXCH*KK];
    int bid = blockIdx.x;
    int b = bid >> 6;
    int r = bid & 63;
    int gc0, nch, T, isfast;
    if (r < 16) { isfast = 1; gc0 = r * 16; nch = 16; T = TFAST; }
    else {
        int s = r - 16;
        int c0s = (s < 32) ? (43 * s) : (1376 + 42 * (s - 32));
        nch = (s < 32) ? 43 : 42;
        gc0 = CF + c0s; T = TSLOW; isfast = 0;
    }
    int tid = threadIdx.x;

    const float4* base = isfast
        ? ((const float4*)fastp + (size_t)(b * CF + gc0) * TFAST * NQ4)
        : ((const float4*)slowp + (size_t)(b * CSL + (gc0 - CF)) * TSLOW * NQ4);
    const float scale = 1.f / (float)T;
    int ntasks = nch * NQ4;
    for (int x = tid; x < ntasks; x += 256) {
        int cl = x / NQ4;
        int q  = x - cl * NQ4;
        const float4* p = base + (size_t)cl * T * NQ4 + q;
        float4 a = make_float4(0.f, 0.f, 0.f, 0.f);
        #pragma unroll 8
        for (int t = 0; t < T; ++t) {
            float4 v = p[t * NQ4];
            a.x += v.x; a.y += v.y; a.z += v.z; a.w += v.w;
        }
        a.x *= scale; a.y *= scale; a.z *= scale; a.w *= scale;
        ((float4*)sfeat)[cl * NQ4 + q] = a;
    }
    const float4* wsrc = (const float4*)Wc + (size_t)gc0 * (KK / 4);
    int wtasks = nch * (KK / 4);
    for (int x = tid; x < wtasks; x += 256) ((float4*)sW)[x] = wsrc[x];
    __syncthreads();

    int cg = tid & 31;
    int kq = tid >> 5;            // k0 = kq*10
    float acc[7][10];
    #pragma unroll
    for (int j = 0; j < 7; ++j)
        #pragma unroll
        for (int i = 0; i < 10; ++i) acc[j][i] = 0.f;

    const float* fr = sfeat + cg;
    const float* wr = sW + kq * 10;
    for (int c = 0; c < nch; ++c) {
        float w[10];
        #pragma unroll
        for (int i = 0; i < 10; ++i) w[i] = wr[c * KK + i];
        #pragma unroll
        for (int j = 0; j < 7; ++j) {
            float fv = fr[c * HWQ + 32 * j];   // j==6,cg>=4 hits pad: never stored
            #pragma unroll
            for (int i = 0; i < 10; ++i) acc[j][i] += fv * w[i];
        }
    }

    int k0 = kq * 10;
    if (use_partials) {
        // P[r][b][k][cell] — coalesced over cg
        float* P = ws + P_OFF + (size_t)r * G_SIZE + (size_t)b * (KK * HWQ);
        #pragma unroll
        for (int j = 0; j < 7; ++j) {
            int cell = cg + 32 * j;
            if (cell < HWQ) {
                #pragma unroll
                for (int i = 0; i < 10; ++i) P[(k0 + i) * HWQ + cell] = acc[j][i];
            }
        }
    } else {
        float* g = ws + G_OFF + (size_t)b * HWQ * KK;
        #pragma unroll
        for (int j = 0; j < 7; ++j) {
            int cell = cg + 32 * j;
            if (cell < HWQ) {
                #pragma unroll
                for (int i = 0; i < 10; ++i) atomicAdd(&g[cell * KK + k0 + i], acc[j][i]);
            }
        }
    }
}

// ---------------- fallback: zero G (only when ws too small for P) ----------------
__global__ __launch_bounds__(256) void kz_zero(float* __restrict__ ws) {
    int idx = blockIdx.x * 256 + threadIdx.x;
    if (idx < G_SIZE) ws[G_OFF + idx] = 0.f;
}

// ---------------- K2b: reduce partials (blocks 0..122) + IoU assign (block 123) ----
#define RED_BLOCKS ((G_SIZE + 511) / 512)   // 123
__global__ __launch_bounds__(512) void k2b_assign(const float* __restrict__ props,
                                                  const float* __restrict__ gtb,
                                                  float* __restrict__ ws,
                                                  int use_partials) {
    int blk = blockIdx.x;
    int t = threadIdx.x;
    if (blk < RED_BLOCKS) {
        if (!use_partials) return;
        int ridx = blk * 512 + t;            // linear over [b][k][cell]
        if (ridx < G_SIZE) {
            const float* P = ws + P_OFF;
            float s = 0.f;
            #pragma unroll 16
            for (int cs = 0; cs < NSPLIT; ++cs) s += P[(size_t)cs * G_SIZE + ridx];
            int b    = ridx / (KK * HWQ);
            int rem  = ridx - b * (KK * HWQ);
            int k    = rem / HWQ;
            int cell = rem - k * HWQ;
            ws[G_OFF + (size_t)b * HWQ * KK + cell * KK + k] = s;  // G[b][cell][k]
        }
        return;
    }
    // ---- assignment block (512 threads = B*N) ----
    __shared__ float sgt[BB*MM*4];
    __shared__ float sfg[BB*NN];
    __shared__ int sany;
    if (t < BB*MM*4) sgt[t] = gtb[t];
    if (t == 0) sany = 0;
    __syncthreads();
    int b = t >> 7;
    float x1 = props[t*4+0], y1 = props[t*4+1], x2 = props[t*4+2], y2 = props[t*4+3];
    float aa = (x2 - x1) * (y2 - y1);
    float best = -1.f; int arg = 0;
    for (int m = 0; m < MM; ++m) {
        const float* g = &sgt[(b*MM + m)*4];
        float tlx = fmaxf(x1, g[0]), tly = fmaxf(y1, g[1]);
        float brx = fminf(x2, g[2]), bry = fminf(y2, g[3]);
        float inter = fmaxf(brx - tlx, 0.f) * fmaxf(bry - tly, 0.f);
        float ab = (g[2] - g[0]) * (g[3] - g[1]);
        float iou = inter / (aa + ab - inter);
        if (iou > best) { best = iou; arg = m; }   // first-max = argmax semantics
    }
    if (best >= 0.85f) atomicOr(&sany, 1);
    __syncthreads();
    float fg = sany ? (best >= 0.85f ? 1.f : 0.f) : (best >= 0.5f ? 1.f : 0.f);
    sfg[t] = fg;
    ws[FGF_OFF + t] = fg;
    ((int*)ws)[ASSIGN_OFF + t] = arg;
    __syncthreads();
    if (t < BB) {
        float s = 0.f;
        for (int i = 0; i < NN; ++i) s += sfg[t*NN + i];
        ws[CNT_OFF + t] = s;
        ws[NUM_OFF + t] = 0.f;
    }
    if (t == 0) ((int*)ws)[CTR_OFF] = 0;
}

// ---------------- K3b: per-proposal loss + last-block finalize ----------------
__device__ __forceinline__ float logsig(float x) {
    return fminf(x, 0.f) - log1pf(expf(-fabsf(x)));
}

__global__ __launch_bounds__(128) void k3b_loss(const float* __restrict__ props,
                                                const float* __restrict__ gtc,
                                                const float* __restrict__ bcls,
                                                float* __restrict__ ws,
                                                float* __restrict__ out) {
    int p = blockIdx.x;
    int b = p >> 7;
    int t = threadIdx.x;
    __shared__ int cells[49];
    __shared__ float red[128];
    if (ws[FGF_OFF + p] != 0.f) {
        if (t < 49) {
            int gy = t / 7, gx = t % 7;
            float x1 = props[p*4+0] * (1.f/16.f);
            float y1 = props[p*4+1] * (1.f/16.f);
            float x2 = props[p*4+2] * (1.f/16.f);
            float y2 = props[p*4+3] * (1.f/16.f);
            float gry = ((float)gy + 0.5f) / 7.f;
            float grx = ((float)gx + 0.5f) / 7.f;
            float cy = y1 + gry * (y2 - y1);
            float cx = x1 + grx * (x2 - x1);
            int iy = (int)floorf(cy); iy = min(max(iy, 0), HH-1);
            int ix = (int)floorf(cx); ix = min(max(ix, 0), WW-1);
            cells[t] = iy * WW + ix;
        }
        __syncthreads();
        float lk = 0.f;
        if (t < KK) {
            float a = 0.f;
            const float* Gb = ws + G_OFF + b * HWQ * KK + t;
            #pragma unroll 7
            for (int g = 0; g < 49; ++g) a += Gb[cells[g] * KK];
            float logit = a * (1.f/49.f) + bcls[t];
            int asg = ((const int*)ws)[ASSIGN_OFF + p];
            float y = gtc[(b*MM + asg)*KK + t];
            lk = -(y * logsig(logit) + (1.f - y) * logsig(-logit));
        }
        red[t] = lk;
        __syncthreads();
        for (int s = 64; s > 0; s >>= 1) {
            if (t < s) red[t] += red[t + s];
            __syncthreads();
        }
        if (t == 0) atomicAdd(&ws[NUM_OFF + b], red[0] * (1.f/KK));
    }
    if (t == 0) {
        __threadfence();
        int old = atomicAdd(&((int*)ws)[CTR_OFF], 1);
        if (old == BB*NN - 1) {
            __threadfence();
            #pragma unroll
            for (int bb = 0; bb < BB; ++bb) {
                float num = atomicAdd(&ws[NUM_OFF + bb], 0.f);
                float c = ws[CNT_OFF + bb];
                out[bb] = (c > 0.f) ? num / c : 0.f;
            }
        }
    }
}

extern "C" void kernel_launch(void* const* d_in, const int* in_sizes, int n_in,
                              void* d_out, int out_size, void* d_ws, size_t ws_size,
                              hipStream_t stream) {
    const float* fastp = (const float*)d_in[0];
    const float* slowp = (const float*)d_in[1];
    const float* props = (const float*)d_in[2];
    const float* gtb   = (const float*)d_in[3];
    const float* gtc   = (const float*)d_in[4];
    const float* Wc    = (const float*)d_in[5];
    const float* bcls  = (const float*)d_in[6];
    float* ws  = (float*)d_ws;
    float* out = (float*)d_out;

    const size_t need = (size_t)(P_OFF + P_SIZE) * sizeof(float);
    const int use_partials = (ws_size >= need) ? 1 : 0;   // deterministic -> graph-safe

    if (!use_partials)
        kz_zero<<<(G_SIZE + 255)/256, 256, 0, stream>>>(ws);
    k12_fused<<<BB * NSPLIT, 256, 0, stream>>>(fastp, slowp, Wc, ws, use_partials);
    k2b_assign<<<RED_BLOCKS + 1, 512, 0, stream>>>(props, gtb, ws, use_partials);
    k3b_loss<<<BB*NN, 128, 0, stream>>>(props, gtc, bcls, ws, out);
}